// Round 6
// baseline (189.396 us; speedup 1.0000x reference)
//
#include <hip/hip_runtime.h>
#include <stdint.h>

#define M_ROWS 12608   // 64 * 197
#define K_DIM  768
#define RANK   192
#define BM     32
#define BN     192     // full chunk width -> block owns whole output rows
#define BK     32
#define NKT    (K_DIM / BK)   // 24
#define NMT    (M_ROWS / BM)  // 394 exact

typedef __attribute__((ext_vector_type(8))) short  short8;
typedef __attribute__((ext_vector_type(4))) float  float4v;

static __device__ __forceinline__ unsigned short f2bf(float f) {
    union { float f; uint32_t u; } v; v.f = f;
    uint32_t u = v.u;
    uint32_t r = u + 0x7FFFu + ((u >> 16) & 1u);   // round-to-nearest-even
    return (unsigned short)(r >> 16);
}

// ---------------------------------------------------------------------------
// Kernel 1: W [768][192] fp32 (x3 chunks) -> Wt [576][768] bf16 (transposed)
// ---------------------------------------------------------------------------
__global__ void convW_kernel(const float* __restrict__ wq, const float* __restrict__ wk,
                             const float* __restrict__ wv, unsigned short* __restrict__ Wt) {
    __shared__ float tile[32][33];
    const int ch = blockIdx.z;
    const float* w = (ch == 0) ? wq : (ch == 1) ? wk : wv;
    const int k0 = blockIdx.x * 32;
    const int r0 = blockIdx.y * 32;
    const int tj = threadIdx.x & 31;
    const int ti = threadIdx.x >> 5;   // 0..7
#pragma unroll
    for (int p = 0; p < 4; ++p) {
        int i = ti + p * 8;
        tile[i][tj] = w[(size_t)(k0 + i) * RANK + r0 + tj];   // coalesced in r
    }
    __syncthreads();
#pragma unroll
    for (int p = 0; p < 4; ++p) {
        int i = ti + p * 8;                                    // r-offset
        Wt[(size_t)(ch * RANK + r0 + i) * K_DIM + k0 + tj] = f2bf(tile[tj][i]); // coalesced in k
    }
}

// ---------------------------------------------------------------------------
// Kernel 2: out[ch][m][r] = gelu( X[m][:] . Wt[ch*192+r][:] )
// 256 threads = 4 waves, each wave covers all 32 rows x 48 cols (wn = wid).
// Block tile 32 x 192, BK=32 -> LDS rows are 64 B; swizzle ((row>>1)&3)<<4
// gives worst-case 2-way bank aliasing (free on CDNA4).
// LDS: A 2x2KB + B 2x12KB = 28 KB -> 5 blocks/CU, 20 waves/CU.
// Grid 1200: xcd=id&7, j=id>>3, ch=j%3, mtile=(id&7)+8*(j/3)  (guard >=394).
// The 3 chunk-blocks sharing an mtile's X rows land on ONE XCD (round-5
// validated pattern: FETCH 128->32 MB). Full-row output ownership restores
// round-1's exact WRITE=output behavior.
// ---------------------------------------------------------------------------
__global__ __launch_bounds__(256, 5) void gemm_gelu_kernel(
        const float* __restrict__ X, const unsigned short* __restrict__ Wt,
        float* __restrict__ out) {
    const int id    = blockIdx.x;
    const int j     = id >> 3;                 // 0..149
    const int ch    = j % 3;                   // chunk
    const int mtile = (id & 7) + 8 * (j / 3);  // 0..399
    if (mtile >= NMT) return;

    __shared__ unsigned short Al[2][BM * BK];  // 2 KB each
    __shared__ unsigned short Bl[2][BN * BK];  // 12 KB each

    const int tid  = threadIdx.x;
    const int lane = tid & 63;
    const int wid  = tid >> 6;                 // 0..3 = wn

    // ---- A staging: 256 chunks of 4 fp32 (16 B); thread t -> chunk t ----
    const int a_row   = tid >> 3;              // 0..31
    const int a_kc    = tid & 7;               // 0..7 (4-float chunk)
    const size_t a_gb = (size_t)(mtile * BM + a_row) * K_DIM + a_kc * 4;
    const int a_laddr = a_row * 64 + ((a_kc * 8) ^ (((a_row >> 1) & 3) << 4));

    // ---- B staging: 768 chunks of 8 bf16 (16 B); thread t -> t, t+256, t+512
    int b_laddr[3];
    size_t b_gb[3];
#pragma unroll
    for (int i = 0; i < 3; ++i) {
        int c   = tid + i * 256;
        int row = c >> 2;                      // 0..191 (n within chunk)
        int kc  = c & 3;                       // 16-B slot within 64-B row
        b_laddr[i] = row * 64 + ((kc * 16) ^ (((row >> 1) & 3) << 4));
        b_gb[i]    = (size_t)(ch * RANK + row) * K_DIM + kc * 8;
    }

    float4v rA;
    int4 rB[3];

    auto LOADA = [&](int kt) {
        rA = *reinterpret_cast<const float4v*>(X + a_gb + (size_t)kt * BK);
    };
    auto LOADB = [&](int kt) {
#pragma unroll
        for (int i = 0; i < 3; ++i)
            rB[i] = *reinterpret_cast<const int4*>(Wt + b_gb[i] + (size_t)kt * BK);
    };
    auto WRITEBUF = [&](int buf) {
        uint32_t w0 = (uint32_t)f2bf(rA[0]) | ((uint32_t)f2bf(rA[1]) << 16);
        uint32_t w1 = (uint32_t)f2bf(rA[2]) | ((uint32_t)f2bf(rA[3]) << 16);
        int2 aw; aw.x = (int)w0; aw.y = (int)w1;
        *reinterpret_cast<int2*>(reinterpret_cast<char*>(&Al[buf][0]) + a_laddr) = aw;
        char* bb = reinterpret_cast<char*>(&Bl[buf][0]);
#pragma unroll
        for (int i = 0; i < 3; ++i)
            *reinterpret_cast<int4*>(bb + b_laddr[i]) = rB[i];
    };

    float4v acc[2][3];
#pragma unroll
    for (int mf = 0; mf < 2; ++mf)
#pragma unroll
        for (int nf = 0; nf < 3; ++nf)
            acc[mf][nf] = (float4v)(0.0f);

    const int kslot = (lane >> 4) * 16;        // byte offset of this lane's 8 bf16
    auto COMPUTE = [&](int buf) {
        const char* ab = reinterpret_cast<const char*>(&Al[buf][0]);
        const char* bb = reinterpret_cast<const char*>(&Bl[buf][0]);
        short8 afr[2], bfr[3];
#pragma unroll
        for (int mf = 0; mf < 2; ++mf) {
            int row = mf * 16 + (lane & 15);
            afr[mf] = *reinterpret_cast<const short8*>(ab + row * 64 + (kslot ^ (((row >> 1) & 3) << 4)));
        }
#pragma unroll
        for (int nf = 0; nf < 3; ++nf) {
            int row = wid * 48 + nf * 16 + (lane & 15);
            bfr[nf] = *reinterpret_cast<const short8*>(bb + row * 64 + (kslot ^ (((row >> 1) & 3) << 4)));
        }
#pragma unroll
        for (int mf = 0; mf < 2; ++mf)
#pragma unroll
            for (int nf = 0; nf < 3; ++nf)
                acc[mf][nf] = __builtin_amdgcn_mfma_f32_16x16x32_bf16(
                    afr[mf], bfr[nf], acc[mf][nf], 0, 0, 0);
    };

    // ---- pipeline: regs hold tile kt+1 at the top of iter kt ----
    LOADA(0); LOADB(0);
    WRITEBUF(0);
    LOADA(1); LOADB(1);
    __syncthreads();

    for (int kt = 0; kt < NKT; ++kt) {
        const int cur = kt & 1;
        if (kt + 1 < NKT) WRITEBUF(cur ^ 1);                 // stage tile kt+1
        if (kt + 2 < NKT) { LOADA(kt + 2); LOADB(kt + 2); }  // prefetch kt+2
        COMPUTE(cur);
        __syncthreads();
    }

    // ---- epilogue: exact gelu, fp32 store (block owns full 768-B rows) ----
    const float inv_sqrt2 = 0.70710678118654752f;
    const size_t obase = (size_t)ch * ((size_t)M_ROWS * RANK);
#pragma unroll
    for (int mf = 0; mf < 2; ++mf) {
        const int mrow0 = mtile * BM + mf * 16 + ((lane >> 4) << 2);
#pragma unroll
        for (int nf = 0; nf < 3; ++nf) {
            const int ncol = wid * 48 + nf * 16 + (lane & 15);
#pragma unroll
            for (int r = 0; r < 4; ++r) {
                float x = acc[mf][nf][r];
                float g = 0.5f * x * (1.0f + erff(x * inv_sqrt2));
                out[obase + (size_t)(mrow0 + r) * RANK + ncol] = g;
            }
        }
    }
}

// ---------------------------------------------------------------------------
extern "C" void kernel_launch(void* const* d_in, const int* in_sizes, int n_in,
                              void* d_out, int out_size, void* d_ws, size_t ws_size,
                              hipStream_t stream) {
    const float* X  = (const float*)d_in[0];
    const float* wq = (const float*)d_in[1];
    const float* wk = (const float*)d_in[2];
    const float* wv = (const float*)d_in[3];
    unsigned short* Wt = (unsigned short*)d_ws;   // 576*768*2 = 884,736 B
    float* out = (float*)d_out;

    convW_kernel<<<dim3(24, 6, 3), 256, 0, stream>>>(wq, wk, wv, Wt);
    gemm_gelu_kernel<<<dim3(1200), 256, 0, stream>>>(X, Wt, out);
}

// Round 8
// 109.805 us; speedup vs baseline: 1.7248x; 1.7248x over previous
//
#include <hip/hip_runtime.h>
#include <stdint.h>

#define M_ROWS 12608   // 64 * 197
#define K_DIM  768
#define RANK   192
#define BM     64
#define BK     64
#define NKT    (K_DIM / BK)   // 12

typedef __attribute__((ext_vector_type(8))) short  short8;
typedef __attribute__((ext_vector_type(4))) float  float4v;

static __device__ __forceinline__ unsigned short f2bf(float f) {
    union { float f; uint32_t u; } v; v.f = f;
    uint32_t u = v.u;
    uint32_t r = u + 0x7FFFu + ((u >> 16) & 1u);   // round-to-nearest-even
    return (unsigned short)(r >> 16);
}

// ---------------------------------------------------------------------------
// Kernel 1: W [768][192] fp32 (x3 chunks) -> Wt [576][768] bf16 (transposed)
// ---------------------------------------------------------------------------
__global__ void convW_kernel(const float* __restrict__ wq, const float* __restrict__ wk,
                             const float* __restrict__ wv, unsigned short* __restrict__ Wt) {
    __shared__ float tile[32][33];
    const int ch = blockIdx.z;
    const float* w = (ch == 0) ? wq : (ch == 1) ? wk : wv;
    const int k0 = blockIdx.x * 32;
    const int r0 = blockIdx.y * 32;
    const int tj = threadIdx.x & 31;
    const int ti = threadIdx.x >> 5;   // 0..7
#pragma unroll
    for (int p = 0; p < 4; ++p) {
        int i = ti + p * 8;
        tile[i][tj] = w[(size_t)(k0 + i) * RANK + r0 + tj];   // coalesced in r
    }
    __syncthreads();
#pragma unroll
    for (int p = 0; p < 4; ++p) {
        int i = ti + p * 8;                                    // r-offset
        Wt[(size_t)(ch * RANK + r0 + i) * K_DIM + k0 + tj] = f2bf(tile[tj][i]); // coalesced in k
    }
}

// ---------------------------------------------------------------------------
// Kernel 2: out[ch][m][r] = gelu( X[m][:] . Wt[ch*192+r][:] )
// ROUND-1 STRUCTURE (measured 45 us, WRITE exact): 512 thr = 8 waves (2Mx4N),
// block tile 64 x 192 (full chunk), BK=64, 64 KB LDS dbuf, XOR swizzle.
// Round-7 deltas only:
//   (1) XCD swizzle: the 3 chunk-sharers of one mtile at ids (m%8)+8*(3*(m/8)+c)
//       -> same id%8 -> same XCD (r5-validated: X fetched once into that L2).
//   (2) nontemporal output stores: bypass L2, no piecemeal dirty evictions.
// ---------------------------------------------------------------------------
__global__ __launch_bounds__(512, 2) void gemm_gelu_kernel(
        const float* __restrict__ X, const unsigned short* __restrict__ Wt,
        float* __restrict__ out) {
    const int id    = blockIdx.x;              // 0..599
    const int j     = id >> 3;                 // 0..74
    const int ch    = j % 3;                   // chunk
    const int mtile = (id & 7) + 8 * (j / 3);  // 0..199
    if (mtile >= 197) return;

    __shared__ unsigned short Al[2][BM * BK];     // 8 KB each
    __shared__ unsigned short Bl[2][RANK * BK];   // 24 KB each

    const int tid  = threadIdx.x;
    const int lane = tid & 63;
    const int wid  = tid >> 6;      // 0..7
    const int wm   = wid >> 2;      // 0..1
    const int wn   = wid & 3;       // 0..3

    // ---- staging address precompute ----
    // A: thread t loads 8 consecutive fp32 of row ar at k-chunk (t&7)*8
    const int ar      = tid >> 3;                      // 0..63
    const int acb     = (tid & 7) * 16;                // byte col in 128B row
    const size_t a_gb = (size_t)(mtile * BM + ar) * K_DIM + (tid & 7) * 8;
    const int a_laddr = ar * 128 + (acb ^ ((ar & 7) << 4));

    // B: 1536 chunks of 8 bf16; thread t handles chunks t, t+512, t+1024
    int b_laddr[3];
    size_t b_gb[3];
#pragma unroll
    for (int i = 0; i < 3; ++i) {
        int c  = tid + i * 512;
        int br = c >> 3;                               // 0..191 (n-local)
        int kb = (c & 7) * 16;
        b_laddr[i] = br * 128 + (kb ^ ((br & 7) << 4));
        b_gb[i]    = (size_t)(ch * RANK + br) * K_DIM + (c & 7) * 8;
    }

    float4v rA0, rA1;
    int4 rB0, rB1, rB2;

    auto LOADA = [&](int kt) {
        const float* p = X + a_gb + (size_t)kt * BK;
        rA0 = *reinterpret_cast<const float4v*>(p);
        rA1 = *reinterpret_cast<const float4v*>(p + 4);
    };
    auto LOADB = [&](int kt) {
        rB0 = *reinterpret_cast<const int4*>(Wt + b_gb[0] + (size_t)kt * BK);
        rB1 = *reinterpret_cast<const int4*>(Wt + b_gb[1] + (size_t)kt * BK);
        rB2 = *reinterpret_cast<const int4*>(Wt + b_gb[2] + (size_t)kt * BK);
    };
    auto WRITEBUF = [&](int buf) {
        uint32_t w0 = (uint32_t)f2bf(rA0[0]) | ((uint32_t)f2bf(rA0[1]) << 16);
        uint32_t w1 = (uint32_t)f2bf(rA0[2]) | ((uint32_t)f2bf(rA0[3]) << 16);
        uint32_t w2 = (uint32_t)f2bf(rA1[0]) | ((uint32_t)f2bf(rA1[1]) << 16);
        uint32_t w3 = (uint32_t)f2bf(rA1[2]) | ((uint32_t)f2bf(rA1[3]) << 16);
        int4 aw; aw.x = (int)w0; aw.y = (int)w1; aw.z = (int)w2; aw.w = (int)w3;
        char* ab = reinterpret_cast<char*>(&Al[buf][0]);
        *reinterpret_cast<int4*>(ab + a_laddr) = aw;
        char* bb = reinterpret_cast<char*>(&Bl[buf][0]);
        *reinterpret_cast<int4*>(bb + b_laddr[0]) = rB0;
        *reinterpret_cast<int4*>(bb + b_laddr[1]) = rB1;
        *reinterpret_cast<int4*>(bb + b_laddr[2]) = rB2;
    };

    float4v acc[2][3];
#pragma unroll
    for (int mf = 0; mf < 2; ++mf)
#pragma unroll
        for (int nf = 0; nf < 3; ++nf)
            acc[mf][nf] = (float4v)(0.0f);

    auto COMPUTE = [&](int buf) {
        const char* ab = reinterpret_cast<const char*>(&Al[buf][0]);
        const char* bb = reinterpret_cast<const char*>(&Bl[buf][0]);
#pragma unroll
        for (int ks = 0; ks < 2; ++ks) {
            const int kb = ks * 64 + ((lane >> 4) << 4);
            short8 afr[2], bfr[3];
#pragma unroll
            for (int mf = 0; mf < 2; ++mf) {
                int row = wm * 32 + mf * 16 + (lane & 15);
                afr[mf] = *reinterpret_cast<const short8*>(ab + row * 128 + (kb ^ ((row & 7) << 4)));
            }
#pragma unroll
            for (int nf = 0; nf < 3; ++nf) {
                int row = wn * 48 + nf * 16 + (lane & 15);
                bfr[nf] = *reinterpret_cast<const short8*>(bb + row * 128 + (kb ^ ((row & 7) << 4)));
            }
#pragma unroll
            for (int mf = 0; mf < 2; ++mf)
#pragma unroll
                for (int nf = 0; nf < 3; ++nf)
                    acc[mf][nf] = __builtin_amdgcn_mfma_f32_16x16x32_bf16(
                        afr[mf], bfr[nf], acc[mf][nf], 0, 0, 0);
        }
    };

    // ---- pipeline: regs hold tile kt+1 at the top of iter kt ----
    LOADA(0); LOADB(0);
    WRITEBUF(0);
    LOADA(1); LOADB(1);
    __syncthreads();

    for (int kt = 0; kt < NKT; ++kt) {
        const int cur = kt & 1;
        if (kt + 1 < NKT) WRITEBUF(cur ^ 1);                 // stage tile kt+1
        if (kt + 2 < NKT) { LOADA(kt + 2); LOADB(kt + 2); }  // prefetch kt+2
        COMPUTE(cur);
        __syncthreads();
    }

    // ---- epilogue: exact gelu, fp32 NONTEMPORAL store ----
    const float inv_sqrt2 = 0.70710678118654752f;
    const size_t obase = (size_t)ch * ((size_t)M_ROWS * RANK);
#pragma unroll
    for (int mf = 0; mf < 2; ++mf) {
        const int mrow0 = mtile * BM + wm * 32 + mf * 16 + ((lane >> 4) << 2);
#pragma unroll
        for (int nf = 0; nf < 3; ++nf) {
            const int ncol = wn * 48 + nf * 16 + (lane & 15);
#pragma unroll
            for (int r = 0; r < 4; ++r) {
                float x = acc[mf][nf][r];
                float g = 0.5f * x * (1.0f + erff(x * inv_sqrt2));
                __builtin_nontemporal_store(g, &out[obase + (size_t)(mrow0 + r) * RANK + ncol]);
            }
        }
    }
}

// ---------------------------------------------------------------------------
extern "C" void kernel_launch(void* const* d_in, const int* in_sizes, int n_in,
                              void* d_out, int out_size, void* d_ws, size_t ws_size,
                              hipStream_t stream) {
    const float* X  = (const float*)d_in[0];
    const float* wq = (const float*)d_in[1];
    const float* wk = (const float*)d_in[2];
    const float* wv = (const float*)d_in[3];
    unsigned short* Wt = (unsigned short*)d_ws;   // 576*768*2 = 884,736 B
    float* out = (float*)d_out;

    convW_kernel<<<dim3(24, 6, 3), 256, 0, stream>>>(wq, wk, wv, Wt);
    gemm_gelu_kernel<<<dim3(600), 512, 0, stream>>>(X, Wt, out);
}

// Round 9
// 109.340 us; speedup vs baseline: 1.7322x; 1.0042x over previous
//
#include <hip/hip_runtime.h>
#include <stdint.h>

#define M_ROWS 12608   // 64 * 197
#define K_DIM  768
#define RANK   192
#define BM     64
#define BK     64
#define NKT    (K_DIM / BK)   // 12

typedef __attribute__((ext_vector_type(8))) short  short8;
typedef __attribute__((ext_vector_type(4))) float  float4v;

static __device__ __forceinline__ unsigned short f2bf(float f) {
    union { float f; uint32_t u; } v; v.f = f;
    uint32_t u = v.u;
    uint32_t r = u + 0x7FFFu + ((u >> 16) & 1u);   // round-to-nearest-even
    return (unsigned short)(r >> 16);
}

// Raw barrier WITHOUT vmcnt drain: this wave's LDS ops (reads+writes) drained,
// global prefetch loads stay in flight across the barrier (T4 pattern).
#define SYNC_LDS()  do {                                        \
    asm volatile("s_waitcnt lgkmcnt(0)" ::: "memory");          \
    __builtin_amdgcn_s_barrier();                               \
    __builtin_amdgcn_sched_barrier(0);                          \
} while (0)

// ---------------------------------------------------------------------------
// Kernel 1: W [768][192] fp32 (x3 chunks) -> Wt [576][768] bf16 (transposed)
// ---------------------------------------------------------------------------
__global__ void convW_kernel(const float* __restrict__ wq, const float* __restrict__ wk,
                             const float* __restrict__ wv, unsigned short* __restrict__ Wt) {
    __shared__ float tile[32][33];
    const int ch = blockIdx.z;
    const float* w = (ch == 0) ? wq : (ch == 1) ? wk : wv;
    const int k0 = blockIdx.x * 32;
    const int r0 = blockIdx.y * 32;
    const int tj = threadIdx.x & 31;
    const int ti = threadIdx.x >> 5;   // 0..7
#pragma unroll
    for (int p = 0; p < 4; ++p) {
        int i = ti + p * 8;
        tile[i][tj] = w[(size_t)(k0 + i) * RANK + r0 + tj];   // coalesced in r
    }
    __syncthreads();
#pragma unroll
    for (int p = 0; p < 4; ++p) {
        int i = ti + p * 8;                                    // r-offset
        Wt[(size_t)(ch * RANK + r0 + i) * K_DIM + k0 + tj] = f2bf(tile[tj][i]); // coalesced in k
    }
}

// ---------------------------------------------------------------------------
// Kernel 2: out[ch][m][r] = gelu( X[m][:] . Wt[ch*192+r][:] )
// Round-8 structure (traffic-optimal: FETCH 23.5 MB, WRITE 36 MB) +
// round-9 delta: raw-barrier K-loop. __syncthreads() forced
// s_waitcnt vmcnt(0) per iteration, serializing a full load round-trip into
// each of the 12 K-iters (~4000 cyc/iter measured). Now: COMPUTE ->
// WRITEBUF (vmcnt wait lands here, after a full iteration of slack) ->
// LOAD(kt+2) -> lgkmcnt(0)+s_barrier (loads stay in flight).
// ---------------------------------------------------------------------------
__global__ __launch_bounds__(512, 2) void gemm_gelu_kernel(
        const float* __restrict__ X, const unsigned short* __restrict__ Wt,
        float* __restrict__ out) {
    const int id    = blockIdx.x;              // 0..599
    const int j     = id >> 3;                 // 0..74
    const int ch    = j % 3;                   // chunk
    const int mtile = (id & 7) + 8 * (j / 3);  // 0..199
    if (mtile >= 197) return;

    __shared__ unsigned short Al[2][BM * BK];     // 8 KB each
    __shared__ unsigned short Bl[2][RANK * BK];   // 24 KB each

    const int tid  = threadIdx.x;
    const int lane = tid & 63;
    const int wid  = tid >> 6;      // 0..7
    const int wm   = wid >> 2;      // 0..1
    const int wn   = wid & 3;       // 0..3

    // ---- staging address precompute ----
    // A: thread t loads 8 consecutive fp32 of row ar at k-chunk (t&7)*8
    const int ar      = tid >> 3;                      // 0..63
    const int acb     = (tid & 7) * 16;                // byte col in 128B row
    const size_t a_gb = (size_t)(mtile * BM + ar) * K_DIM + (tid & 7) * 8;
    const int a_laddr = ar * 128 + (acb ^ ((ar & 7) << 4));

    // B: 1536 chunks of 8 bf16; thread t handles chunks t, t+512, t+1024
    int b_laddr[3];
    size_t b_gb[3];
#pragma unroll
    for (int i = 0; i < 3; ++i) {
        int c  = tid + i * 512;
        int br = c >> 3;                               // 0..191 (n-local)
        int kb = (c & 7) * 16;
        b_laddr[i] = br * 128 + (kb ^ ((br & 7) << 4));
        b_gb[i]    = (size_t)(ch * RANK + br) * K_DIM + (c & 7) * 8;
    }

    float4v rA0, rA1;
    int4 rB0, rB1, rB2;

    auto LOADA = [&](int kt) {
        const float* p = X + a_gb + (size_t)kt * BK;
        rA0 = *reinterpret_cast<const float4v*>(p);
        rA1 = *reinterpret_cast<const float4v*>(p + 4);
    };
    auto LOADB = [&](int kt) {
        rB0 = *reinterpret_cast<const int4*>(Wt + b_gb[0] + (size_t)kt * BK);
        rB1 = *reinterpret_cast<const int4*>(Wt + b_gb[1] + (size_t)kt * BK);
        rB2 = *reinterpret_cast<const int4*>(Wt + b_gb[2] + (size_t)kt * BK);
    };
    auto WRITEBUF = [&](int buf) {
        uint32_t w0 = (uint32_t)f2bf(rA0[0]) | ((uint32_t)f2bf(rA0[1]) << 16);
        uint32_t w1 = (uint32_t)f2bf(rA0[2]) | ((uint32_t)f2bf(rA0[3]) << 16);
        uint32_t w2 = (uint32_t)f2bf(rA1[0]) | ((uint32_t)f2bf(rA1[1]) << 16);
        uint32_t w3 = (uint32_t)f2bf(rA1[2]) | ((uint32_t)f2bf(rA1[3]) << 16);
        int4 aw; aw.x = (int)w0; aw.y = (int)w1; aw.z = (int)w2; aw.w = (int)w3;
        char* ab = reinterpret_cast<char*>(&Al[buf][0]);
        *reinterpret_cast<int4*>(ab + a_laddr) = aw;
        char* bb = reinterpret_cast<char*>(&Bl[buf][0]);
        *reinterpret_cast<int4*>(bb + b_laddr[0]) = rB0;
        *reinterpret_cast<int4*>(bb + b_laddr[1]) = rB1;
        *reinterpret_cast<int4*>(bb + b_laddr[2]) = rB2;
    };

    float4v acc[2][3];
#pragma unroll
    for (int mf = 0; mf < 2; ++mf)
#pragma unroll
        for (int nf = 0; nf < 3; ++nf)
            acc[mf][nf] = (float4v)(0.0f);

    auto COMPUTE = [&](int buf) {
        const char* ab = reinterpret_cast<const char*>(&Al[buf][0]);
        const char* bb = reinterpret_cast<const char*>(&Bl[buf][0]);
#pragma unroll
        for (int ks = 0; ks < 2; ++ks) {
            const int kb = ks * 64 + ((lane >> 4) << 4);
            short8 afr[2], bfr[3];
#pragma unroll
            for (int mf = 0; mf < 2; ++mf) {
                int row = wm * 32 + mf * 16 + (lane & 15);
                afr[mf] = *reinterpret_cast<const short8*>(ab + row * 128 + (kb ^ ((row & 7) << 4)));
            }
#pragma unroll
            for (int nf = 0; nf < 3; ++nf) {
                int row = wn * 48 + nf * 16 + (lane & 15);
                bfr[nf] = *reinterpret_cast<const short8*>(bb + row * 128 + (kb ^ ((row & 7) << 4)));
            }
#pragma unroll
            for (int mf = 0; mf < 2; ++mf)
#pragma unroll
                for (int nf = 0; nf < 3; ++nf)
                    acc[mf][nf] = __builtin_amdgcn_mfma_f32_16x16x32_bf16(
                        afr[mf], bfr[nf], acc[mf][nf], 0, 0, 0);
        }
    };

    // ---- prologue: buf0 = tile 0; regs = tile 1 ----
    LOADA(0); LOADB(0);
    WRITEBUF(0);
    LOADA(1); LOADB(1);
    SYNC_LDS();

    // ---- K-loop: COMPUTE -> stage next -> prefetch next+1 -> raw barrier ----
    for (int kt = 0; kt < NKT; ++kt) {
        const int cur = kt & 1;
        COMPUTE(cur);                                         // reads tile kt
        if (kt + 1 < NKT) WRITEBUF(cur ^ 1);                  // stage tile kt+1
        if (kt + 2 < NKT) { LOADA(kt + 2); LOADB(kt + 2); }   // prefetch kt+2
        if (kt + 1 < NKT) SYNC_LDS();                         // loads stay in flight
    }

    // ---- epilogue: exact gelu, fp32 NONTEMPORAL store ----
    const float inv_sqrt2 = 0.70710678118654752f;
    const size_t obase = (size_t)ch * ((size_t)M_ROWS * RANK);
#pragma unroll
    for (int mf = 0; mf < 2; ++mf) {
        const int mrow0 = mtile * BM + wm * 32 + mf * 16 + ((lane >> 4) << 2);
#pragma unroll
        for (int nf = 0; nf < 3; ++nf) {
            const int ncol = wn * 48 + nf * 16 + (lane & 15);
#pragma unroll
            for (int r = 0; r < 4; ++r) {
                float x = acc[mf][nf][r];
                float g = 0.5f * x * (1.0f + erff(x * inv_sqrt2));
                __builtin_nontemporal_store(g, &out[obase + (size_t)(mrow0 + r) * RANK + ncol]);
            }
        }
    }
}

// ---------------------------------------------------------------------------
extern "C" void kernel_launch(void* const* d_in, const int* in_sizes, int n_in,
                              void* d_out, int out_size, void* d_ws, size_t ws_size,
                              hipStream_t stream) {
    const float* X  = (const float*)d_in[0];
    const float* wq = (const float*)d_in[1];
    const float* wk = (const float*)d_in[2];
    const float* wv = (const float*)d_in[3];
    unsigned short* Wt = (unsigned short*)d_ws;   // 576*768*2 = 884,736 B
    float* out = (float*)d_out;

    convW_kernel<<<dim3(24, 6, 3), 256, 0, stream>>>(wq, wk, wv, Wt);
    gemm_gelu_kernel<<<dim3(600), 512, 0, stream>>>(X, Wt, out);
}